// Round 7
// baseline (244.723 us; speedup 1.0000x reference)
//
#include <hip/hip_runtime.h>
#include <cstdint>
#include <cstddef>

// FeatureAttention: x[4,2048,1024] fp32; Q=xWq^T+bq, K=xWk^T+bk, V=xWv^T+bv;
// out = softmax(QK^T/32) V.  bf16 MFMA pipeline.
//
// R11 = R10 (issue-early double-buffer, proven +20%) with BK 64->32 so LDS
// drops 66->33 KB and occupancy rises 2->4 blocks/CU (R9 proved this tile
// runs at 33 KB). 4 waves/SIMD now cover barrier/LDS-read stalls that R10's
// 2 waves/SIMD exposed. Per-tile MFMA:ds_read ratio unchanged (16:8).
//   prologue: stage(0); syncthreads
//   iter t:   stage(t+1) -> buf[(t+1)&1]   (issued FIRST, hidden under compute)
//             compute(t) from buf[t&1]
//             __syncthreads()
//   tail:     compute(NT-1)
// Swizzle (P=4): 16B chunk c of row r stored at slot (c+r)&3, applied on the
// staging *source* chunk; read pos = ((fg+frow)&3) — balanced across banks.
//
// Workspace (80 MB):
//   [0,16M)  Xb    [16,20) Wqkb (Wq|Wk stacked)  [20,22) Wvb
//   [32,64M) QKb   [8192][2048]: Q cols 0-1023, K cols 1024-2047
//   [64,80M) Vt    (V transposed [1024][8192])
//   [0,32M)  Sc    (exp(scores) bf16 [4][2048][2048], reuses dead region)

typedef unsigned short ushort_t;
typedef __attribute__((ext_vector_type(8))) short short8;
typedef __attribute__((ext_vector_type(4))) float f32x4;

#define AS1 __attribute__((address_space(1)))
#define AS3 __attribute__((address_space(3)))

__device__ __forceinline__ ushort_t f2bf(float f) {
    unsigned int u = __float_as_uint(f);
    u += 0x7FFFu + ((u >> 16) & 1u);
    return (ushort_t)(u >> 16);
}
__device__ __forceinline__ float bf2f(ushort_t b) {
    return __uint_as_float(((unsigned)b) << 16);
}

// async global->LDS, 16B/lane; lds dest = wave-uniform base + lane*16
__device__ __forceinline__ void async_ld16(const void* g, unsigned lds_off) {
    __builtin_amdgcn_global_load_lds((const AS1 void*)(uintptr_t)g,
                                     (AS3 void*)(uintptr_t)lds_off,
                                     16, 0, 0);
}

// ---------------------------------------------------------------------------
// Double-buffered BT-GEMM, 128x128 tile, BK=32, 256 threads (4 waves 2x2).
//   C[m*ldc+n] = epi( scale * sum_k A[m*lda+k] * B[n*ldb+k] )
// EPI: 1 +bias(n): n<1024 ? bias0[n] : bias1[n-1024]
//      2 +bias0[m] | 3 exp(v) | 4 v / rowsum(A-tile row m) (in-kernel rowsum)
// CX,CY: XCD chunk dims (bijective remap; NCX*NCY*NCZ must equal 8).
// ---------------------------------------------------------------------------
template <typename OT, int EPI, int CX, int CY>
__global__ __launch_bounds__(256, 4) void gemm_db(
    const ushort_t* __restrict__ A, const ushort_t* __restrict__ B,
    const float* __restrict__ bias0, const float* __restrict__ bias1,
    OT* __restrict__ C, int K, int lda, int ldb, int ldc, float scale,
    long long aOffZ, long long bOffZ, long long cOffZ)
{
    constexpr int BK = 32;

    __shared__ __align__(16) ushort_t As[2][128 * BK];
    __shared__ __align__(16) ushort_t Bs[2][128 * BK];
    __shared__ float rs[128];       // EPI==4 only

    const int tid  = threadIdx.x;
    const int wave = tid >> 6;
    const int lane = tid & 63;

    // ---- bijective XCD-chunked remap (XCD = linear%8) ----
    const int GX  = gridDim.x, GY = gridDim.y, GZ = gridDim.z;
    const int bid = blockIdx.x + GX * (blockIdx.y + GY * blockIdx.z);
    const int xcd = bid & 7;
    const int jj  = bid >> 3;
    const int CZ  = (GX * GY * GZ) / (8 * CX * CY);
    const int NCX = GX / CX, NCY = GY / CY;
    const int cx  = xcd % NCX;
    const int ct  = xcd / NCX;
    const int cy  = ct % NCY, cz = ct / NCY;
    const int bx  = cx * CX + (jj % CX);
    const int by  = cy * CY + ((jj / CX) % CY);
    const int bz  = cz * CZ + jj / (CX * CY);

    A += (size_t)bz * aOffZ;
    B += (size_t)bz * bOffZ;

    const int m0 = by * 128;
    const int n0 = bx * 128;
    const int wm = (wave >> 1) * 64;
    const int wn = (wave & 1) * 64;

    const unsigned aB0 = (unsigned)(uintptr_t)&As[0][0];
    const unsigned aB1 = (unsigned)(uintptr_t)&As[1][0];
    const unsigned bB0 = (unsigned)(uintptr_t)&Bs[0][0];
    const unsigned bB1 = (unsigned)(uintptr_t)&Bs[1][0];

    // staging map: 64 rows/call (16 rows/wave), 4 chunks of 16B per row
    const int srow = wave * 16 + (lane >> 2);
    const int cd   = ((lane & 3) - srow) & 3;     // swizzled source chunk
    const unsigned lw = (unsigned)(wave << 10);

    const ushort_t* gA = A + (size_t)(m0 + srow) * lda + cd * 8;
    const ushort_t* gB = B + (size_t)(n0 + srow) * ldb + cd * 8;

    // stage K-tile t into buf t&1 (4 calls: 2 A + 2 B)
    auto stage = [&](int t) {
        const int buf = t & 1;
        const ushort_t* pA = gA + (size_t)t * BK;
        const ushort_t* pB = gB + (size_t)t * BK;
        const unsigned la = (buf ? aB1 : aB0) + lw;
        const unsigned lb = (buf ? bB1 : bB0) + lw;
#pragma unroll
        for (int c = 0; c < 2; ++c) {
            async_ld16(pA + (size_t)(c * 64) * lda, la + c * 4096);
            async_ld16(pB + (size_t)(c * 64) * ldb, lb + c * 4096);
        }
    };

    // fragment map: lane -> row l&15; k-chunk fg at swizzled pos (fg+row)&3
    const int frow = lane & 15;
    const int fg   = lane >> 4;

    const int NT = K / BK;

    f32x4 acc[4][4] = {};
    float rsacc[4] = {0.f, 0.f, 0.f, 0.f};

    // one K-tile of compute from buffer `buf` (16 MFMA, 8 ds_read_b128)
    auto compute = [&](int buf) {
        const ushort_t* Aw = &As[buf][0];
        const ushort_t* Bw = &Bs[buf][0];
        const int pa = ((fg + frow) & 3) << 3;
        short8 af[4], bf[4];
#pragma unroll
        for (int i = 0; i < 4; ++i)
            af[i] = *(const short8*)&Aw[(wm + i * 16 + frow) * BK + pa];
        if (EPI == 4 && wn == 0) {   // rowsum of the streamed A tile
#pragma unroll
            for (int i = 0; i < 4; ++i)
#pragma unroll
                for (int e = 0; e < 8; ++e)
                    rsacc[i] += bf2f((ushort_t)af[i][e]);
        }
#pragma unroll
        for (int j = 0; j < 4; ++j)
            bf[j] = *(const short8*)&Bw[(wn + j * 16 + frow) * BK + pa];
#pragma unroll
        for (int i = 0; i < 4; ++i)
#pragma unroll
            for (int j = 0; j < 4; ++j)
                acc[i][j] = __builtin_amdgcn_mfma_f32_16x16x32_bf16(
                    af[i], bf[j], acc[i][j], 0, 0, 0);
    };

    // prologue: stage tile 0, full drain once
    stage(0);
    __syncthreads();

    for (int t = 0; t < NT - 1; ++t) {
        stage(t + 1);        // issued early: latency hidden under compute(t)
        compute(t & 1);
        __syncthreads();     // tile t+1 landed; all waves done with buf[t&1]
    }
    compute((NT - 1) & 1);   // tail

    if (EPI == 4) {
        if (wn == 0) {
#pragma unroll
            for (int i = 0; i < 4; ++i) {
                float s = rsacc[i];
                s += __shfl_xor(s, 16, 64);   // combine fg 0<->1
                s += __shfl_xor(s, 32, 64);   // combine fg pairs
                rs[wm + i * 16 + frow] = s;   // 4 lanes, same value/addr
            }
        }
        __syncthreads();
    }

    // C/D layout: lane l reg r -> row (l>>4)*4+r, col l&15
    C += (size_t)bz * cOffZ;
    const int r0 = fg << 2;
    const int c0 = lane & 15;
#pragma unroll
    for (int i = 0; i < 4; ++i) {
        float bm[4];
        if (EPI == 2) {
#pragma unroll
            for (int r = 0; r < 4; ++r)
                bm[r] = bias0[m0 + wm + i * 16 + r0 + r];
        }
        if (EPI == 4) {
#pragma unroll
            for (int r = 0; r < 4; ++r)
                bm[r] = 1.0f / rs[wm + i * 16 + r0 + r];
        }
#pragma unroll
        for (int j = 0; j < 4; ++j) {
            const int n = n0 + wn + j * 16 + c0;
            float bn = 0.f;
            if (EPI == 1) bn = (n < 1024) ? bias0[n] : bias1[n - 1024];
#pragma unroll
            for (int r = 0; r < 4; ++r) {
                const int m = m0 + wm + i * 16 + r0 + r;
                float v = acc[i][j][r] * scale;
                if (EPI == 1) v += bn;
                if (EPI == 2) v += bm[r];
                if (EPI == 3) v = __expf(v);
                if (EPI == 4) v *= bm[r];
                if constexpr (sizeof(OT) == 2)
                    C[(size_t)m * ldc + n] = f2bf(v);
                else
                    C[(size_t)m * ldc + n] = v;
            }
        }
    }
}

// one-shot fp32->bf16 cast of x, Wq, Wk, Wv (block-range dispatch)
__global__ __launch_bounds__(256) void cvt_all(
    const float* __restrict__ x,  const float* __restrict__ wq,
    const float* __restrict__ wk, const float* __restrict__ wv,
    ushort_t* __restrict__ xb,  ushort_t* __restrict__ wqb,
    ushort_t* __restrict__ wkb, ushort_t* __restrict__ wvb)
{
    const int b = blockIdx.x;
    const float* src; ushort_t* dst; size_t base;
    if (b < 4096)      { src = x;  dst = xb;  base = (size_t)b * 2048; }
    else if (b < 4608) { src = wq; dst = wqb; base = (size_t)(b - 4096) * 2048; }
    else if (b < 5120) { src = wk; dst = wkb; base = (size_t)(b - 4608) * 2048; }
    else               { src = wv; dst = wvb; base = (size_t)(b - 5120) * 2048; }
    const size_t i = base + threadIdx.x * 8;
    const f32x4 a = *(const f32x4*)(src + i);
    const f32x4 c = *(const f32x4*)(src + i + 4);
    short8 o;
    o[0] = (short)f2bf(a[0]); o[1] = (short)f2bf(a[1]);
    o[2] = (short)f2bf(a[2]); o[3] = (short)f2bf(a[3]);
    o[4] = (short)f2bf(c[0]); o[5] = (short)f2bf(c[1]);
    o[6] = (short)f2bf(c[2]); o[7] = (short)f2bf(c[3]);
    *(short8*)(dst + i) = o;
}

extern "C" void kernel_launch(void* const* d_in, const int* in_sizes, int n_in,
                              void* d_out, int out_size, void* d_ws, size_t ws_size,
                              hipStream_t stream)
{
    const float* x  = (const float*)d_in[0];
    const float* Wq = (const float*)d_in[1];
    const float* bq = (const float*)d_in[2];
    const float* Wk = (const float*)d_in[3];
    const float* bk = (const float*)d_in[4];
    const float* Wv = (const float*)d_in[5];
    const float* bv = (const float*)d_in[6];
    float* out = (float*)d_out;

    char* ws = (char*)d_ws;
    const size_t MB = 1ull << 20;
    ushort_t* Xb   = (ushort_t*)(ws);
    ushort_t* Wqkb = (ushort_t*)(ws + 16 * MB);  // Wq rows 0-1023 | Wk rows 1024-2047
    ushort_t* Wvb  = (ushort_t*)(ws + 20 * MB);
    ushort_t* QKb  = (ushort_t*)(ws + 32 * MB);  // [8192][2048]: Q | K
    ushort_t* Vt   = (ushort_t*)(ws + 64 * MB);  // [1024][8192]
    ushort_t* Sc   = (ushort_t*)(ws);            // reuses dead Xb/W region

    // 1) all casts in one launch (wq -> ws+16M, wk -> ws+18M: stacked Wqkb)
    cvt_all<<<dim3(5632), dim3(256), 0, stream>>>(
        x, Wq, Wk, Wv, Xb, Wqkb, (ushort_t*)(ws + 18 * MB), Wvb);

    // 2) QK projection: A=Xb [8192x1024], B=Wqkb [2048x1024] -> QKb [8192x2048]
    //    grid 16x64=1024; chunk 8x x 16y (A 4MB + B 2MB per XCD)
    gemm_db<ushort_t, 1, 8, 16><<<dim3(16, 64, 1), dim3(256), 0, stream>>>(
        Xb, Wqkb, bq, bk, QKb, 1024, 1024, 1024, 2048, 1.0f, 0, 0, 0);

    // 3) Vt = Wv X^T + bv(row)  [1024,8192]
    //    grid 64x8=512; chunk 16x x 4y (A 1MB + B 4MB per XCD)
    gemm_db<ushort_t, 2, 16, 4><<<dim3(64, 8, 1), dim3(256), 0, stream>>>(
        Wvb, Xb, bv, nullptr, Vt, 1024, 1024, 1024, 8192, 1.0f, 0, 0, 0);

    // 4) Sc = exp(Q K^T / 32) per batch (max-free softmax numerator)
    //    grid 16x16x4=1024; chunk 8x x 16y x 1z (Q 4MB + K 2MB per XCD)
    gemm_db<ushort_t, 3, 8, 16><<<dim3(16, 16, 4), dim3(256), 0, stream>>>(
        QKb, QKb + 1024, nullptr, nullptr, Sc, 1024, 2048, 2048, 2048,
        0.03125f, 2048ll * 2048, 2048ll * 2048, 2048ll * 2048);

    // 5) out = (Sc Vt^T) / rowsum(Sc row), rowsum fused in-kernel
    //    grid 8x16x4=512; chunk 8x x 8y x 1z (Sc 4MB + Vt 4MB per XCD)
    gemm_db<float, 4, 8, 8><<<dim3(8, 16, 4), dim3(256), 0, stream>>>(
        Sc, Vt, nullptr, nullptr, out, 2048, 2048, 8192, 1024, 1.0f,
        2048ll * 2048, 2048ll, 2048ll * 1024);
}